// Round 14
// baseline (142.434 us; speedup 1.0000x reference)
//
#include <hip/hip_runtime.h>
#include <hip/hip_bf16.h>
#include <stdint.h>
#include <stddef.h>

#define B_  4
#define S_  2048
#define D_  1024
#define TB_ 128

typedef float v4f  __attribute__((ext_vector_type(4)));
typedef short s16x4 __attribute__((ext_vector_type(4)));
typedef short s16x8 __attribute__((ext_vector_type(8)));

#define WAITV(n) asm volatile("s_waitcnt vmcnt(" #n ")" ::: "memory")

__device__ __forceinline__ unsigned short f2bf(float f) {
  union { float f; unsigned u; } x; x.f = f;
  unsigned u = x.u;
  unsigned r = (u + 0x7FFFu + ((u >> 16) & 1u)) >> 16;
  return (unsigned short)r;
}

__device__ __forceinline__ void gld16(const void* g, void* l) {
  __builtin_amdgcn_global_load_lds(
      (const __attribute__((address_space(1))) unsigned int*)g,
      (__attribute__((address_space(3))) unsigned int*)l, 16, 0, 0);
}

// raw barrier (no vmcnt(0) drain) + motion fence
__device__ __forceinline__ void barrier_sync() {
  asm volatile("" ::: "memory");
  __builtin_amdgcn_s_barrier();
  asm volatile("" ::: "memory");
  __builtin_amdgcn_sched_barrier(0);
}

// ---------------- prep: gate + cvt(Q) + cvt(K) + V^T, one dispatch --------
__global__ __launch_bounds__(256) void prep_kernel(
    const float* __restrict__ Q, const float* __restrict__ K,
    const float* __restrict__ V, const float* __restrict__ tb,
    const float* __restrict__ W, const float* __restrict__ bias,
    short* __restrict__ Qb, short* __restrict__ Kb,
    short* __restrict__ VT, float* __restrict__ gate) {
  __shared__ float tile[64][65];
  int bid = blockIdx.x;
  int t = threadIdx.x;
  if (bid < 16384) {                       // bulk f32->bf16 convert (Q or K)
    const float* src = bid < 8192 ? Q : K;
    short* dst = bid < 8192 ? Qb : Kb;
    size_t g = (size_t)(bid & 8191) * 256 + t;
    v4f v = *(const v4f*)(src + g * 4);
    s16x4 o;
    o[0] = (short)f2bf(v[0]); o[1] = (short)f2bf(v[1]);
    o[2] = (short)f2bf(v[2]); o[3] = (short)f2bf(v[3]);
    *(s16x4*)(dst + g * 4) = o;
  } else if (bid < 18432) {                // V [b][s][d] -> V^T [b][d][s]
    int v = bid - 16384;
    int b = v >> 9;
    int rem = v & 511;
    int s0 = (rem & 31) * 64, d0 = (rem >> 5) * 64;
    int tc = t & 63, tr4 = t >> 6;
    const float* src = V + ((size_t)b * S_ + s0) * D_ + d0;
    #pragma unroll
    for (int p = 0; p < 16; ++p) {
      int r = p * 4 + tr4;
      tile[r][tc] = src[(size_t)r * D_ + tc];
    }
    __syncthreads();
    short* dst = VT + ((size_t)b * D_ + d0) * S_ + s0;
    #pragma unroll
    for (int p = 0; p < 16; ++p) {
      int r = p * 4 + tr4;
      dst[(size_t)r * S_ + tc] = (short)f2bf(tile[tc][r]);
    }
  } else {                                 // gate: sigmoid(tb @ W + b)
    int b = t >> 6, l = t & 63;
    float s = tb[b * TB_ + l] * W[l] + tb[b * TB_ + 64 + l] * W[64 + l];
    #pragma unroll
    for (int off = 32; off > 0; off >>= 1) s += __shfl_down(s, off, 64);
    if (l == 0) gate[b] = 1.0f / (1.0f + __expf(-(s + bias[0])));
  }
}

// ---------------- ring-3 fine-phase GEMM: C = A(256xK) . B(128xK)^T -------
// Tile 256x128, 512 threads = 8 waves (4M x 2N), wave 64x64 (MFR=NFR=4,
// 16x16x32). Ring of 3 one-K-tile buffers (A 32K + B 16K = 48K each; 144KB
// total). 4 phases per K-tile; phase q: {ds_reads (B 8x at q=0, A 2x) ->
// stage one half of K-tile kt+2 into buf (kt+2)%3 -> vmcnt(6) at q=3 only
// -> barrier -> lgkmcnt(0)+sched_barrier -> setprio 8xMFMA -> barrier}.
// Ledger: staged buffer differs from both consumed buffers (ring-3);
// WAITV(6)@ph3 guarantees all stages >=3 phases old have landed, i.e.
// kt+1's data (staged kt-1 ph0-2) lands before its first read; write-
// after-read separated by kt-1 ph3's trailing barrier (lgkm0 precedes
// MFMA precedes barrier). Never drains vmcnt to 0 until the tail.
template<int TN, int KT, int BROWS, int LDC, bool GATED>
__global__ __launch_bounds__(512, 1) void gemm_ring(
    const short* __restrict__ Ag, const short* __restrict__ Bg,
    const float* __restrict__ gate, float* __restrict__ Cg) {
  extern __shared__ char lds[];
  constexpr int NKT = KT / 64;            // K-tiles
  constexpr int BUFB = 3 * 16384;         // 48 KB per K-tile buffer
  constexpr int PB = 8 * TN;              // tiles per batch
  constexpr int CPX = (4 * PB) / 8;       // wgs per XCD chunk

  int wg = blockIdx.x;
  int swz = (wg & 7) * CPX + (wg >> 3);   // bijective (grid % 8 == 0)
  int b = swz / PB;
  int rem = swz % PB;
  int m0 = (rem / TN) * 256;
  int n0 = (rem % TN) * 128;

  int tid = threadIdx.x;
  int w = tid >> 6, l = tid & 63;
  int wm = w >> 1, wn = w & 1;
  int l7 = l & 7, fr = l & 15, hi = l >> 4;

  const short* Ab = Ag + (size_t)b * S_ * KT + (size_t)m0 * KT;
  const short* Bb = Bg + (size_t)b * BROWS * KT + (size_t)n0 * KT;

  // staging: linear LDS dest; inverse-swizzled global chunk (rule 21)
  int schunk = ((tid & 7) ^ ((tid >> 3) & 7)) * 8;  // shorts

  // stage one 16KB half: h=0/1 -> A rows h*128..+128; h=2 -> B rows 0..127
  auto stage_half = [&](int tt, int h, int tgtbuf) {
    char* base = lds + tgtbuf * BUFB + h * 16384;
    const short* src = (h < 2)
        ? (Ab + (size_t)(h * 128 + (tid >> 3)) * KT)
        : (Bb + (size_t)(tid >> 3) * KT);
    src += (size_t)tt * 64 + schunk;
    gld16(src, base + tid * 16);
    gld16(src + (size_t)64 * KT, base + 8192 + tid * 16);
  };

  v4f acc[4][4];
  #pragma unroll
  for (int m = 0; m < 4; ++m)
    #pragma unroll
    for (int n = 0; n < 4; ++n)
      #pragma unroll
      for (int j = 0; j < 4; ++j) acc[m][n][j] = 0.0f;

  // prologue: stage K-tiles 0 and 1; wait for tile 0 (6 loads in flight).
  #pragma unroll
  for (int tt = 0; tt < 2; ++tt)
    #pragma unroll
    for (int h = 0; h < 3; ++h) stage_half(tt, h, tt);
  WAITV(6);
  barrier_sync();

  int bufc = 0;                            // kt % 3
  for (int kt = 0; kt < NKT; ++kt) {
    const char* bb = lds + bufc * BUFB;
    int tgt = bufc + 2; if (tgt >= 3) tgt -= 3;
    bool stage_on = (kt < NKT - 2);
    s16x8 bf[4][2];
    #pragma unroll
    for (int q = 0; q < 4; ++q) {
      if (q == 0) {
        #pragma unroll
        for (int nf = 0; nf < 4; ++nf) {
          int rb = wn * 64 + nf * 16 + fr;   // 0..127
          const char* rp = bb + 32768 + (size_t)rb * 128;
          bf[nf][0] = *(const s16x8*)(rp + ((0 + hi) ^ l7) * 16);
          bf[nf][1] = *(const s16x8*)(rp + ((4 + hi) ^ l7) * 16);
        }
      }
      s16x8 af[2];
      {
        int ra = wm * 64 + q * 16 + fr;      // 0..255
        const char* rp = bb + (ra >> 7) * 16384 + (size_t)(ra & 127) * 128;
        af[0] = *(const s16x8*)(rp + ((0 + hi) ^ l7) * 16);
        af[1] = *(const s16x8*)(rp + ((4 + hi) ^ l7) * 16);
      }
      if (stage_on && q < 3) stage_half(kt + 2, q, tgt);
      if (q == 3) {
        if (kt < NKT - 2) { WAITV(6); } else { WAITV(0); }
      }
      barrier_sync();
      asm volatile("s_waitcnt lgkmcnt(0)" ::: "memory");
      __builtin_amdgcn_sched_barrier(0);
      __builtin_amdgcn_s_setprio(1);
      #pragma unroll
      for (int nf = 0; nf < 4; ++nf) {
        acc[q][nf] = __builtin_amdgcn_mfma_f32_16x16x32_bf16(
            af[0], bf[nf][0], acc[q][nf], 0, 0, 0);
        acc[q][nf] = __builtin_amdgcn_mfma_f32_16x16x32_bf16(
            af[1], bf[nf][1], acc[q][nf], 0, 0, 0);
      }
      __builtin_amdgcn_s_setprio(0);
      barrier_sync();
    }
    if (++bufc == 3) bufc = 0;
  }

  float g = 1.0f;
  if constexpr (GATED) g = gate[b] * 0.03125f;   // sigmoid-gate / sqrt(1024)
  float* Cb = Cg + (size_t)b * S_ * LDC +
              (size_t)(m0 + wm * 64) * LDC + n0 + wn * 64;
  #pragma unroll
  for (int mf = 0; mf < 4; ++mf)
    #pragma unroll
    for (int nf = 0; nf < 4; ++nf) {
      int r0 = mf * 16 + hi * 4;
      int c = nf * 16 + fr;
      #pragma unroll
      for (int j = 0; j < 4; ++j)
        Cb[(size_t)(r0 + j) * LDC + c] = acc[mf][nf][j] * g;
    }
}

// ---------------- row softmax: f32 in-place + bf16 copy for PV ------------
__global__ __launch_bounds__(256) void softmax_kernel(
    float* __restrict__ attn, short* __restrict__ attnb) {
  size_t row = blockIdx.x;
  float* p = attn + row * S_;
  int t = threadIdx.x;
  v4f v0 = *(const v4f*)(p + t * 8);
  v4f v1 = *(const v4f*)(p + t * 8 + 4);
  float m = fmaxf(fmaxf(fmaxf(v0[0], v0[1]), fmaxf(v0[2], v0[3])),
                  fmaxf(fmaxf(v1[0], v1[1]), fmaxf(v1[2], v1[3])));
  #pragma unroll
  for (int off = 32; off > 0; off >>= 1) m = fmaxf(m, __shfl_xor(m, off, 64));
  __shared__ float rm[4], rs[4];
  if ((t & 63) == 0) rm[t >> 6] = m;
  __syncthreads();
  m = fmaxf(fmaxf(rm[0], rm[1]), fmaxf(rm[2], rm[3]));
  float e[8]; float sum = 0.0f;
  #pragma unroll
  for (int j = 0; j < 4; ++j) { e[j] = __expf(v0[j] - m); sum += e[j]; }
  #pragma unroll
  for (int j = 0; j < 4; ++j) { e[4 + j] = __expf(v1[j] - m); sum += e[4 + j]; }
  #pragma unroll
  for (int off = 32; off > 0; off >>= 1) sum += __shfl_xor(sum, off, 64);
  if ((t & 63) == 0) rs[t >> 6] = sum;
  __syncthreads();
  sum = rs[0] + rs[1] + rs[2] + rs[3];
  float inv = 1.0f / sum;
  #pragma unroll
  for (int j = 0; j < 4; ++j) v0[j] = e[j] * inv;
  #pragma unroll
  for (int j = 0; j < 4; ++j) v1[j] = e[4 + j] * inv;
  *(v4f*)(p + t * 8) = v0;
  *(v4f*)(p + t * 8 + 4) = v1;
  s16x8 ob;
  ob[0] = (short)f2bf(v0[0]); ob[1] = (short)f2bf(v0[1]);
  ob[2] = (short)f2bf(v0[2]); ob[3] = (short)f2bf(v0[3]);
  ob[4] = (short)f2bf(v1[0]); ob[5] = (short)f2bf(v1[1]);
  ob[6] = (short)f2bf(v1[2]); ob[7] = (short)f2bf(v1[3]);
  *(s16x8*)(attnb + row * S_ + t * 8) = ob;
}

extern "C" void kernel_launch(void* const* d_in, const int* in_sizes, int n_in,
                              void* d_out, int out_size, void* d_ws, size_t ws_size,
                              hipStream_t stream) {
  (void)in_sizes; (void)n_in; (void)out_size; (void)ws_size;
  const float* Q  = (const float*)d_in[0];
  const float* K  = (const float*)d_in[1];
  const float* V  = (const float*)d_in[2];
  const float* tb = (const float*)d_in[3];
  const float* W  = (const float*)d_in[4];
  const float* bias = (const float*)d_in[5];

  float* out  = (float*)d_out;                       // [4,2048,1024]
  float* attn = out + (size_t)B_ * S_ * D_;          // [4,2048,2048]

  char* ws = (char*)d_ws;
  float* gate = (float*)ws;                          // 4 floats
  short* Qb = (short*)(ws + 256);                    // bf16 [4][2048][1024]
  short* Kb = Qb + (size_t)B_ * S_ * D_;             // bf16 [4][2048][1024]
  short* VT = Kb + (size_t)B_ * S_ * D_;             // bf16 [4][1024][2048]
  short* attnb = Qb;                                 // reuse Qb+Kb: bf16 P

  // QK: TN=16 (N=2048), grid 512 (2 cohorts/CU), gated.
  auto* qkf = gemm_ring<16, 1024, 2048, 2048, true>;
  // PV: TN=8 (N=1024), grid 256, K=2048 (32 K-tiles).
  auto* pvf = gemm_ring<8, 2048, 1024, 1024, false>;
  constexpr int G_LDS = 3 * 3 * 16384;               // 147456
  (void)hipFuncSetAttribute((const void*)qkf,
      hipFuncAttributeMaxDynamicSharedMemorySize, G_LDS);
  (void)hipFuncSetAttribute((const void*)pvf,
      hipFuncAttributeMaxDynamicSharedMemorySize, G_LDS);

  prep_kernel<<<18433, 256, 0, stream>>>(Q, K, V, tb, W, bias,
                                         Qb, Kb, VT, gate);
  qkf<<<512, 512, G_LDS, stream>>>(Qb, Kb, gate, attn);
  softmax_kernel<<<8192, 256, 0, stream>>>(attn, attnb);
  pvf<<<256, 512, G_LDS, stream>>>(attnb, VT, gate, out);
}

// Round 15
// 138.156 us; speedup vs baseline: 1.0310x; 1.0310x over previous
//
#include <hip/hip_runtime.h>
#include <hip/hip_bf16.h>
#include <stdint.h>
#include <stddef.h>

#define B_  4
#define S_  2048
#define D_  1024
#define TB_ 128

typedef float v4f  __attribute__((ext_vector_type(4)));
typedef float v16f __attribute__((ext_vector_type(16)));
typedef short s16x4 __attribute__((ext_vector_type(4)));
typedef short s16x8 __attribute__((ext_vector_type(8)));

#define WAITV(n) asm volatile("s_waitcnt vmcnt(" #n ")" ::: "memory")

__device__ __forceinline__ unsigned short f2bf(float f) {
  union { float f; unsigned u; } x; x.f = f;
  unsigned u = x.u;
  unsigned r = (u + 0x7FFFu + ((u >> 16) & 1u)) >> 16;
  return (unsigned short)r;
}

__device__ __forceinline__ float bf2f(unsigned short s) {
  union { unsigned u; float f; } x;
  x.u = (unsigned)s << 16;
  return x.f;
}

__device__ __forceinline__ void gld16(const void* g, void* l) {
  __builtin_amdgcn_global_load_lds(
      (const __attribute__((address_space(1))) unsigned int*)g,
      (__attribute__((address_space(3))) unsigned int*)l, 16, 0, 0);
}

// raw barrier (no vmcnt(0) drain) + motion fence
__device__ __forceinline__ void barrier_sync() {
  asm volatile("" ::: "memory");
  __builtin_amdgcn_s_barrier();
  asm volatile("" ::: "memory");
  __builtin_amdgcn_sched_barrier(0);
}

// ---------------- prep: gate + cvt(Q) + cvt(K) + V^T, one dispatch --------
__global__ __launch_bounds__(256) void prep_kernel(
    const float* __restrict__ Q, const float* __restrict__ K,
    const float* __restrict__ V, const float* __restrict__ tb,
    const float* __restrict__ W, const float* __restrict__ bias,
    short* __restrict__ Qb, short* __restrict__ Kb,
    short* __restrict__ VT, float* __restrict__ gate) {
  __shared__ float tile[64][65];
  int bid = blockIdx.x;
  int t = threadIdx.x;
  if (bid < 16384) {                       // bulk f32->bf16 convert (Q or K)
    const float* src = bid < 8192 ? Q : K;
    short* dst = bid < 8192 ? Qb : Kb;
    size_t g = (size_t)(bid & 8191) * 256 + t;
    v4f v = *(const v4f*)(src + g * 4);
    s16x4 o;
    o[0] = (short)f2bf(v[0]); o[1] = (short)f2bf(v[1]);
    o[2] = (short)f2bf(v[2]); o[3] = (short)f2bf(v[3]);
    *(s16x4*)(dst + g * 4) = o;
  } else if (bid < 18432) {                // V [b][s][d] -> V^T [b][d][s]
    int v = bid - 16384;
    int b = v >> 9;
    int rem = v & 511;
    int s0 = (rem & 31) * 64, d0 = (rem >> 5) * 64;
    int tc = t & 63, tr4 = t >> 6;
    const float* src = V + ((size_t)b * S_ + s0) * D_ + d0;
    #pragma unroll
    for (int p = 0; p < 16; ++p) {
      int r = p * 4 + tr4;
      tile[r][tc] = src[(size_t)r * D_ + tc];
    }
    __syncthreads();
    short* dst = VT + ((size_t)b * D_ + d0) * S_ + s0;
    #pragma unroll
    for (int p = 0; p < 16; ++p) {
      int r = p * 4 + tr4;
      dst[(size_t)r * S_ + tc] = (short)f2bf(tile[tc][r]);
    }
  } else {                                 // gate: sigmoid(tb @ W + b)
    int b = t >> 6, l = t & 63;
    float s = tb[b * TB_ + l] * W[l] + tb[b * TB_ + 64 + l] * W[64 + l];
    #pragma unroll
    for (int off = 32; off > 0; off >>= 1) s += __shfl_down(s, off, 64);
    if (l == 0) gate[b] = 1.0f / (1.0f + __expf(-(s + bias[0])));
  }
}

// ---------------- pipelined GEMM (32x32x16 MFMA): C = A . B^T -------------
// R9's verified structure (best measured): BK=64, 2 LDS buffers, counted
// vmcnt, XOR slot swizzle (rule 21), setprio clusters. WATT adds an
// epilogue that writes 32 rows of the f32 attention-weights output as the
// exact widening of the bf16 P matrix (each block owns rows
// m0+(rem&7)*32 .. +32 — disjoint, full coverage at PB=64).
template<int MFR, int NFR, int WNC, int BLOADS, int KT, int BROWS, int LDC,
         bool GATED, bool WATT>
__global__ __launch_bounds__(512, 2) void gemm_pipe(
    const short* __restrict__ Ag, const short* __restrict__ Bg,
    const float* __restrict__ gate, float* __restrict__ Cg,
    const short* __restrict__ Pfull, float* __restrict__ attnOut) {
  extern __shared__ char lds[];
  constexpr int NT = KT / 64;             // K-tiles
  constexpr int BN = WNC * NFR * 32;      // B-tile rows
  constexpr int ABYTES = 256 * 128;       // 32 KB per K-tile
  constexpr int BBYTES = BN * 128;
  constexpr int BUFB = ABYTES + BBYTES;

  int wg = blockIdx.x;
  int swz = (wg & 7) * 32 + (wg >> 3);    // 256 wgs -> bijective XCD chunk
  int b = swz >> 6;
  int rem = swz & 63;
  int m0 = (rem >> 3) * 256;
  int n0 = (rem & 7) * BN;

  int tid = threadIdx.x;
  int w = tid >> 6, l = tid & 63;
  int wm = w / WNC, wn = w % WNC;
  int l7 = l & 7, col31 = l & 31, hi2 = l >> 5;

  const short* Ab = Ag + (size_t)b * S_ * KT + (size_t)m0 * KT;
  const short* Bb = Bg + (size_t)b * BROWS * KT + (size_t)n0 * KT;

  // staging: linear LDS dest; inverse-swizzled global chunk (rule #21)
  int srow8 = l >> 3;
  int schunk = (l7 ^ srow8) * 8;          // shorts

  v16f acc[MFR][NFR];
  #pragma unroll
  for (int m = 0; m < MFR; ++m)
    #pragma unroll
    for (int n = 0; n < NFR; ++n)
      #pragma unroll
      for (int j = 0; j < 16; ++j) acc[m][n][j] = 0.0f;

  auto stage = [&](int t, int buf) {
    char* La = lds + buf * BUFB;
    char* Lb = La + ABYTES;
    const short* As = Ab + (size_t)t * 64 + schunk;
    #pragma unroll
    for (int j = 0; j < 4; ++j) {
      int blk = w * 4 + j;
      gld16(As + (size_t)(blk * 8 + srow8) * KT, La + blk * 1024);
    }
    const short* Bs = Bb + (size_t)t * 64 + schunk;
    #pragma unroll
    for (int j = 0; j < BLOADS; ++j) {
      int blk = w * BLOADS + j;
      gld16(Bs + (size_t)(blk * 8 + srow8) * KT, Lb + blk * 1024);
    }
  };

  stage(0, 0);
  int cur = 0;
  for (int t = 0; t < NT; ++t) {
    if (t + 1 < NT) {
      stage(t + 1, cur ^ 1);              // prefetch stays in flight
      if constexpr (BLOADS == 4) WAITV(8); else WAITV(6);
    } else {
      WAITV(0);
    }
    barrier_sync();                       // publish tile t
    const char* Abase = lds + cur * BUFB;
    const char* Bbase = Abase + ABYTES;
    #pragma unroll
    for (int ks = 0; ks < 4; ++ks) {
      int slot = ((ks * 2 + hi2) ^ l7) * 16;
      s16x8 bfr[NFR], af[MFR];
      #pragma unroll
      for (int n = 0; n < NFR; ++n)
        bfr[n] = *(const s16x8*)(Bbase +
                 (size_t)(wn * (NFR * 32) + n * 32 + col31) * 128 + slot);
      #pragma unroll
      for (int m = 0; m < MFR; ++m)
        af[m] = *(const s16x8*)(Abase +
                 (size_t)(wm * (MFR * 32) + m * 32 + col31) * 128 + slot);
      __builtin_amdgcn_s_setprio(1);
      #pragma unroll
      for (int m = 0; m < MFR; ++m)
        #pragma unroll
        for (int n = 0; n < NFR; ++n)
          acc[m][n] = __builtin_amdgcn_mfma_f32_32x32x16_bf16(
              af[m], bfr[n], acc[m][n], 0, 0, 0);
      __builtin_amdgcn_s_setprio(0);
    }
    barrier_sync();                       // reads of buf[cur] done
    cur ^= 1;
  }

  float g = 1.0f;
  if constexpr (GATED) g = gate[b] * 0.03125f;   // sigmoid-gate / sqrt(1024)
  float* Cb = Cg + (size_t)b * S_ * LDC +
              (size_t)(m0 + wm * (MFR * 32)) * LDC + n0 + wn * (NFR * 32);
  #pragma unroll
  for (int mf = 0; mf < MFR; ++mf)
    #pragma unroll
    for (int nf = 0; nf < NFR; ++nf) {
      int c = nf * 32 + col31;
      #pragma unroll
      for (int q = 0; q < 4; ++q)
        #pragma unroll
        for (int j = 0; j < 4; ++j) {
          int r = mf * 32 + q * 8 + 4 * hi2 + j;
          Cb[(size_t)r * LDC + c] = acc[mf][nf][q * 4 + j] * g;
        }
    }

  if constexpr (WATT) {
    // write f32 attention-weights = widened bf16 P for this block's
    // 32-row slice (disjoint across blocks; rows m0+ni*32 .. +32).
    int ni = rem & 7;
    const short* Pb = Pfull + (size_t)b * S_ * S_;
    float* Ob = attnOut + (size_t)b * S_ * S_;
    #pragma unroll 4
    for (int r = 0; r < 32; ++r) {
      size_t off = (size_t)(m0 + ni * 32 + r) * S_ + tid * 4;
      s16x4 pv = *(const s16x4*)(Pb + off);
      v4f o;
      o[0] = bf2f((unsigned short)pv[0]);
      o[1] = bf2f((unsigned short)pv[1]);
      o[2] = bf2f((unsigned short)pv[2]);
      o[3] = bf2f((unsigned short)pv[3]);
      *(v4f*)(Ob + off) = o;
    }
  }
}

// ---------------- row softmax: scores(f32) -> bf16 P only -----------------
__global__ __launch_bounds__(256) void softmax_kernel(
    const float* __restrict__ scores, short* __restrict__ attnb) {
  size_t row = blockIdx.x;
  const float* p = scores + row * S_;
  int t = threadIdx.x;
  v4f v0 = *(const v4f*)(p + t * 8);
  v4f v1 = *(const v4f*)(p + t * 8 + 4);
  float m = fmaxf(fmaxf(fmaxf(v0[0], v0[1]), fmaxf(v0[2], v0[3])),
                  fmaxf(fmaxf(v1[0], v1[1]), fmaxf(v1[2], v1[3])));
  #pragma unroll
  for (int off = 32; off > 0; off >>= 1) m = fmaxf(m, __shfl_xor(m, off, 64));
  __shared__ float rm[4], rs[4];
  if ((t & 63) == 0) rm[t >> 6] = m;
  __syncthreads();
  m = fmaxf(fmaxf(rm[0], rm[1]), fmaxf(rm[2], rm[3]));
  float e[8]; float sum = 0.0f;
  #pragma unroll
  for (int j = 0; j < 4; ++j) { e[j] = __expf(v0[j] - m); sum += e[j]; }
  #pragma unroll
  for (int j = 0; j < 4; ++j) { e[4 + j] = __expf(v1[j] - m); sum += e[4 + j]; }
  #pragma unroll
  for (int off = 32; off > 0; off >>= 1) sum += __shfl_xor(sum, off, 64);
  if ((t & 63) == 0) rs[t >> 6] = sum;
  __syncthreads();
  sum = rs[0] + rs[1] + rs[2] + rs[3];
  float inv = 1.0f / sum;
  s16x8 ob;
  #pragma unroll
  for (int j = 0; j < 8; ++j) ob[j] = (short)f2bf(e[j] * inv);
  *(s16x8*)(attnb + row * S_ + t * 8) = ob;
}

extern "C" void kernel_launch(void* const* d_in, const int* in_sizes, int n_in,
                              void* d_out, int out_size, void* d_ws, size_t ws_size,
                              hipStream_t stream) {
  (void)in_sizes; (void)n_in; (void)out_size; (void)ws_size;
  const float* Q  = (const float*)d_in[0];
  const float* K  = (const float*)d_in[1];
  const float* V  = (const float*)d_in[2];
  const float* tb = (const float*)d_in[3];
  const float* W  = (const float*)d_in[4];
  const float* bias = (const float*)d_in[5];

  float* out  = (float*)d_out;                       // [4,2048,1024]
  float* attn = out + (size_t)B_ * S_ * D_;          // [4,2048,2048]: scores,
                                                     // then final weights
  char* ws = (char*)d_ws;
  float* gate = (float*)ws;                          // 4 floats
  short* Qb = (short*)(ws + 256);                    // bf16 [4][2048][1024]
  short* Kb = Qb + (size_t)B_ * S_ * D_;             // bf16 [4][2048][1024]
  short* VT = Kb + (size_t)B_ * S_ * D_;             // bf16 [4][1024][2048]
  short* attnb = Qb;                                 // reuse Qb+Kb: bf16 P

  // QK: tile 256x256 (MFR=4,NFR=2,WNC=4), KT=1024, gated, scores -> attn.
  auto* qkf = gemm_pipe<4, 2, 4, 4, 1024, 2048, 2048, true, false>;
  // PV: tile 256x128 (MFR=2,NFR=2,WNC=2), KT=2048; also writes f32 attn.
  auto* pvf = gemm_pipe<2, 2, 2, 2, 2048, 1024, 1024, false, true>;
  constexpr int QK_LDS = 2 * (256 + 256) * 64 * 2;   // 131072
  constexpr int PV_LDS = 2 * (256 + 128) * 64 * 2;   //  98304
  (void)hipFuncSetAttribute((const void*)qkf,
      hipFuncAttributeMaxDynamicSharedMemorySize, QK_LDS);
  (void)hipFuncSetAttribute((const void*)pvf,
      hipFuncAttributeMaxDynamicSharedMemorySize, PV_LDS);

  prep_kernel<<<18433, 256, 0, stream>>>(Q, K, V, tb, W, bias,
                                         Qb, Kb, VT, gate);
  qkf<<<256, 512, QK_LDS, stream>>>(Qb, Kb, gate, attn, nullptr, nullptr);
  softmax_kernel<<<8192, 256, 0, stream>>>(attn, attnb);
  pvf<<<256, 512, PV_LDS, stream>>>(attnb, VT, gate, out, attnb, attn);
}

// Round 16
// 131.466 us; speedup vs baseline: 1.0834x; 1.0509x over previous
//
#include <hip/hip_runtime.h>
#include <hip/hip_bf16.h>
#include <stdint.h>
#include <stddef.h>

#define B_  4
#define S_  2048
#define D_  1024
#define TB_ 128

typedef float v4f  __attribute__((ext_vector_type(4)));
typedef float v16f __attribute__((ext_vector_type(16)));
typedef short s16x4 __attribute__((ext_vector_type(4)));
typedef short s16x8 __attribute__((ext_vector_type(8)));

#define WAITV(n) asm volatile("s_waitcnt vmcnt(" #n ")" ::: "memory")

__device__ __forceinline__ unsigned short f2bf(float f) {
  union { float f; unsigned u; } x; x.f = f;
  unsigned u = x.u;
  unsigned r = (u + 0x7FFFu + ((u >> 16) & 1u)) >> 16;
  return (unsigned short)r;
}

__device__ __forceinline__ short f2h(float f) {
  union { _Float16 h; short s; } u;
  u.h = (_Float16)f;
  return u.s;
}

__device__ __forceinline__ float h2f(short s) {
  union { short s; _Float16 h; } u;
  u.s = s;
  return (float)u.h;
}

__device__ __forceinline__ void gld16(const void* g, void* l) {
  __builtin_amdgcn_global_load_lds(
      (const __attribute__((address_space(1))) unsigned int*)g,
      (__attribute__((address_space(3))) unsigned int*)l, 16, 0, 0);
}

// raw barrier (no vmcnt(0) drain) + motion fence
__device__ __forceinline__ void barrier_sync() {
  asm volatile("" ::: "memory");
  __builtin_amdgcn_s_barrier();
  asm volatile("" ::: "memory");
  __builtin_amdgcn_sched_barrier(0);
}

// ---------------- prep: gate + cvt(Q) + cvt(K) + V^T, one dispatch --------
__global__ __launch_bounds__(256) void prep_kernel(
    const float* __restrict__ Q, const float* __restrict__ K,
    const float* __restrict__ V, const float* __restrict__ tb,
    const float* __restrict__ W, const float* __restrict__ bias,
    short* __restrict__ Qb, short* __restrict__ Kb,
    short* __restrict__ VT, float* __restrict__ gate) {
  __shared__ float tile[64][65];
  int bid = blockIdx.x;
  int t = threadIdx.x;
  if (bid < 16384) {                       // bulk f32->bf16 convert (Q or K)
    const float* src = bid < 8192 ? Q : K;
    short* dst = bid < 8192 ? Qb : Kb;
    size_t g = (size_t)(bid & 8191) * 256 + t;
    v4f v = *(const v4f*)(src + g * 4);
    s16x4 o;
    o[0] = (short)f2bf(v[0]); o[1] = (short)f2bf(v[1]);
    o[2] = (short)f2bf(v[2]); o[3] = (short)f2bf(v[3]);
    *(s16x4*)(dst + g * 4) = o;
  } else if (bid < 18432) {                // V [b][s][d] -> V^T [b][d][s]
    int v = bid - 16384;
    int b = v >> 9;
    int rem = v & 511;
    int s0 = (rem & 31) * 64, d0 = (rem >> 5) * 64;
    int tc = t & 63, tr4 = t >> 6;
    const float* src = V + ((size_t)b * S_ + s0) * D_ + d0;
    #pragma unroll
    for (int p = 0; p < 16; ++p) {
      int r = p * 4 + tr4;
      tile[r][tc] = src[(size_t)r * D_ + tc];
    }
    __syncthreads();
    short* dst = VT + ((size_t)b * D_ + d0) * S_ + s0;
    #pragma unroll
    for (int p = 0; p < 16; ++p) {
      int r = p * 4 + tr4;
      dst[(size_t)r * S_ + tc] = (short)f2bf(tile[tc][r]);
    }
  } else {                                 // gate: sigmoid(tb @ W + b)
    int b = t >> 6, l = t & 63;
    float s = tb[b * TB_ + l] * W[l] + tb[b * TB_ + 64 + l] * W[64 + l];
    #pragma unroll
    for (int off = 32; off > 0; off >>= 1) s += __shfl_down(s, off, 64);
    if (l == 0) gate[b] = 1.0f / (1.0f + __expf(-(s + bias[0])));
  }
}

// ---------------- pipelined GEMM (32x32x16 MFMA): C = A . B^T -------------
// R9's verified structure (best measured): BK=64, 2 LDS buffers, counted
// vmcnt, XOR slot swizzle (rule 21), setprio clusters. CF16: epilogue
// writes f16 scores (half the write traffic) instead of f32 C.
template<int MFR, int NFR, int WNC, int BLOADS, int KT, int BROWS, int LDC,
         bool GATED, bool CF16>
__global__ __launch_bounds__(512, 2) void gemm_pipe(
    const short* __restrict__ Ag, const short* __restrict__ Bg,
    const float* __restrict__ gate, float* __restrict__ Cg,
    short* __restrict__ Sc) {
  extern __shared__ char lds[];
  constexpr int NT = KT / 64;             // K-tiles
  constexpr int BN = WNC * NFR * 32;      // B-tile rows
  constexpr int ABYTES = 256 * 128;       // 32 KB per K-tile
  constexpr int BBYTES = BN * 128;
  constexpr int BUFB = ABYTES + BBYTES;

  int wg = blockIdx.x;
  int swz = (wg & 7) * 32 + (wg >> 3);    // 256 wgs -> bijective XCD chunk
  int b = swz >> 6;
  int rem = swz & 63;
  int m0 = (rem >> 3) * 256;
  int n0 = (rem & 7) * BN;

  int tid = threadIdx.x;
  int w = tid >> 6, l = tid & 63;
  int wm = w / WNC, wn = w % WNC;
  int l7 = l & 7, col31 = l & 31, hi2 = l >> 5;

  const short* Ab = Ag + (size_t)b * S_ * KT + (size_t)m0 * KT;
  const short* Bb = Bg + (size_t)b * BROWS * KT + (size_t)n0 * KT;

  // staging: linear LDS dest; inverse-swizzled global chunk (rule #21)
  int srow8 = l >> 3;
  int schunk = (l7 ^ srow8) * 8;          // shorts

  v16f acc[MFR][NFR];
  #pragma unroll
  for (int m = 0; m < MFR; ++m)
    #pragma unroll
    for (int n = 0; n < NFR; ++n)
      #pragma unroll
      for (int j = 0; j < 16; ++j) acc[m][n][j] = 0.0f;

  auto stage = [&](int t, int buf) {
    char* La = lds + buf * BUFB;
    char* Lb = La + ABYTES;
    const short* As = Ab + (size_t)t * 64 + schunk;
    #pragma unroll
    for (int j = 0; j < 4; ++j) {
      int blk = w * 4 + j;
      gld16(As + (size_t)(blk * 8 + srow8) * KT, La + blk * 1024);
    }
    const short* Bs = Bb + (size_t)t * 64 + schunk;
    #pragma unroll
    for (int j = 0; j < BLOADS; ++j) {
      int blk = w * BLOADS + j;
      gld16(Bs + (size_t)(blk * 8 + srow8) * KT, Lb + blk * 1024);
    }
  };

  stage(0, 0);
  int cur = 0;
  for (int t = 0; t < NT; ++t) {
    if (t + 1 < NT) {
      stage(t + 1, cur ^ 1);              // prefetch stays in flight
      if constexpr (BLOADS == 4) WAITV(8); else WAITV(6);
    } else {
      WAITV(0);
    }
    barrier_sync();                       // publish tile t
    const char* Abase = lds + cur * BUFB;
    const char* Bbase = Abase + ABYTES;
    #pragma unroll
    for (int ks = 0; ks < 4; ++ks) {
      int slot = ((ks * 2 + hi2) ^ l7) * 16;
      s16x8 bfr[NFR], af[MFR];
      #pragma unroll
      for (int n = 0; n < NFR; ++n)
        bfr[n] = *(const s16x8*)(Bbase +
                 (size_t)(wn * (NFR * 32) + n * 32 + col31) * 128 + slot);
      #pragma unroll
      for (int m = 0; m < MFR; ++m)
        af[m] = *(const s16x8*)(Abase +
                 (size_t)(wm * (MFR * 32) + m * 32 + col31) * 128 + slot);
      __builtin_amdgcn_s_setprio(1);
      #pragma unroll
      for (int m = 0; m < MFR; ++m)
        #pragma unroll
        for (int n = 0; n < NFR; ++n)
          acc[m][n] = __builtin_amdgcn_mfma_f32_32x32x16_bf16(
              af[m], bfr[n], acc[m][n], 0, 0, 0);
      __builtin_amdgcn_s_setprio(0);
    }
    barrier_sync();                       // reads of buf[cur] done
    cur ^= 1;
  }

  float g = 1.0f;
  if constexpr (GATED) g = gate[b] * 0.03125f;   // sigmoid-gate / sqrt(1024)
  if constexpr (CF16) {
    short* Sb = Sc + (size_t)b * S_ * LDC +
                (size_t)(m0 + wm * (MFR * 32)) * LDC + n0 + wn * (NFR * 32);
    #pragma unroll
    for (int mf = 0; mf < MFR; ++mf)
      #pragma unroll
      for (int nf = 0; nf < NFR; ++nf) {
        int c = nf * 32 + col31;
        #pragma unroll
        for (int q = 0; q < 4; ++q)
          #pragma unroll
          for (int j = 0; j < 4; ++j) {
            int r = mf * 32 + q * 8 + 4 * hi2 + j;
            Sb[(size_t)r * LDC + c] = f2h(acc[mf][nf][q * 4 + j] * g);
          }
      }
  } else {
    float* Cb = Cg + (size_t)b * S_ * LDC +
                (size_t)(m0 + wm * (MFR * 32)) * LDC + n0 + wn * (NFR * 32);
    #pragma unroll
    for (int mf = 0; mf < MFR; ++mf)
      #pragma unroll
      for (int nf = 0; nf < NFR; ++nf) {
        int c = nf * 32 + col31;
        #pragma unroll
        for (int q = 0; q < 4; ++q)
          #pragma unroll
          for (int j = 0; j < 4; ++j) {
            int r = mf * 32 + q * 8 + 4 * hi2 + j;
            Cb[(size_t)r * LDC + c] = acc[mf][nf][q * 4 + j] * g;
          }
      }
  }
}

// ---------------- softmax (f16 scores): write f32 attn + bf16 P -----------
__global__ __launch_bounds__(256) void softmax16_kernel(
    const short* __restrict__ Sc, float* __restrict__ attn,
    short* __restrict__ attnb) {
  size_t row = blockIdx.x;
  const short* p = Sc + row * S_;
  int t = threadIdx.x;
  s16x8 raw = *(const s16x8*)(p + t * 8);
  float v[8];
  #pragma unroll
  for (int j = 0; j < 8; ++j) v[j] = h2f(raw[j]);
  float m = v[0];
  #pragma unroll
  for (int j = 1; j < 8; ++j) m = fmaxf(m, v[j]);
  #pragma unroll
  for (int off = 32; off > 0; off >>= 1) m = fmaxf(m, __shfl_xor(m, off, 64));
  __shared__ float rm[4], rs[4];
  if ((t & 63) == 0) rm[t >> 6] = m;
  __syncthreads();
  m = fmaxf(fmaxf(rm[0], rm[1]), fmaxf(rm[2], rm[3]));
  float e[8]; float sum = 0.0f;
  #pragma unroll
  for (int j = 0; j < 8; ++j) { e[j] = __expf(v[j] - m); sum += e[j]; }
  #pragma unroll
  for (int off = 32; off > 0; off >>= 1) sum += __shfl_xor(sum, off, 64);
  if ((t & 63) == 0) rs[t >> 6] = sum;
  __syncthreads();
  sum = rs[0] + rs[1] + rs[2] + rs[3];
  float inv = 1.0f / sum;
  v4f o0, o1;
  s16x8 ob;
  #pragma unroll
  for (int j = 0; j < 4; ++j) { o0[j] = e[j] * inv; ob[j] = (short)f2bf(o0[j]); }
  #pragma unroll
  for (int j = 0; j < 4; ++j) { o1[j] = e[4 + j] * inv; ob[4 + j] = (short)f2bf(o1[j]); }
  float* q = attn + row * S_;
  *(v4f*)(q + t * 8) = o0;
  *(v4f*)(q + t * 8 + 4) = o1;
  *(s16x8*)(attnb + row * S_ + t * 8) = ob;
}

// ---------------- fallback softmax (f32 scores in-place) ------------------
__global__ __launch_bounds__(256) void softmax32_kernel(
    float* __restrict__ attn, short* __restrict__ attnb) {
  size_t row = blockIdx.x;
  float* p = attn + row * S_;
  int t = threadIdx.x;
  v4f v0 = *(const v4f*)(p + t * 8);
  v4f v1 = *(const v4f*)(p + t * 8 + 4);
  float m = fmaxf(fmaxf(fmaxf(v0[0], v0[1]), fmaxf(v0[2], v0[3])),
                  fmaxf(fmaxf(v1[0], v1[1]), fmaxf(v1[2], v1[3])));
  #pragma unroll
  for (int off = 32; off > 0; off >>= 1) m = fmaxf(m, __shfl_xor(m, off, 64));
  __shared__ float rm[4], rs[4];
  if ((t & 63) == 0) rm[t >> 6] = m;
  __syncthreads();
  m = fmaxf(fmaxf(rm[0], rm[1]), fmaxf(rm[2], rm[3]));
  float e[8]; float sum = 0.0f;
  #pragma unroll
  for (int j = 0; j < 4; ++j) { e[j] = __expf(v0[j] - m); sum += e[j]; }
  #pragma unroll
  for (int j = 0; j < 4; ++j) { e[4 + j] = __expf(v1[j] - m); sum += e[4 + j]; }
  #pragma unroll
  for (int off = 32; off > 0; off >>= 1) sum += __shfl_xor(sum, off, 64);
  if ((t & 63) == 0) rs[t >> 6] = sum;
  __syncthreads();
  sum = rs[0] + rs[1] + rs[2] + rs[3];
  float inv = 1.0f / sum;
  s16x8 ob;
  #pragma unroll
  for (int j = 0; j < 4; ++j) { v0[j] = e[j] * inv; ob[j] = (short)f2bf(v0[j]); }
  #pragma unroll
  for (int j = 0; j < 4; ++j) { v1[j] = e[4 + j] * inv; ob[4 + j] = (short)f2bf(v1[j]); }
  *(v4f*)(p + t * 8) = v0;
  *(v4f*)(p + t * 8 + 4) = v1;
  *(s16x8*)(attnb + row * S_ + t * 8) = ob;
}

extern "C" void kernel_launch(void* const* d_in, const int* in_sizes, int n_in,
                              void* d_out, int out_size, void* d_ws, size_t ws_size,
                              hipStream_t stream) {
  (void)in_sizes; (void)n_in; (void)out_size;
  const float* Q  = (const float*)d_in[0];
  const float* K  = (const float*)d_in[1];
  const float* V  = (const float*)d_in[2];
  const float* tb = (const float*)d_in[3];
  const float* W  = (const float*)d_in[4];
  const float* bias = (const float*)d_in[5];

  float* out  = (float*)d_out;                       // [4,2048,1024]
  float* attn = out + (size_t)B_ * S_ * D_;          // [4,2048,2048]

  char* ws = (char*)d_ws;
  float* gate = (float*)ws;                          // 4 floats
  short* Qb = (short*)(ws + 256);                    // bf16 [4][2048][1024]
  short* Kb = Qb + (size_t)B_ * S_ * D_;             // bf16 [4][2048][1024]
  short* VT = Kb + (size_t)B_ * S_ * D_;             // bf16 [4][1024][2048]
  short* Sc = VT + (size_t)B_ * D_ * S_;             // f16 [4][2048][2048]
  short* attnb = Qb;                                 // reuse Qb+Kb: bf16 P

  const size_t NEED_F16 = 256 + (size_t)48 * 1024 * 1024
                              + (size_t)32 * 1024 * 1024;
  bool f16path = ws_size >= NEED_F16;

  // QK variants: f16-score epilogue (preferred) or f32 (fallback).
  auto* qk16 = gemm_pipe<4, 2, 4, 4, 1024, 2048, 2048, true, true>;
  auto* qk32 = gemm_pipe<4, 2, 4, 4, 1024, 2048, 2048, true, false>;
  // PV: tile 256x128 (MFR=2,NFR=2,WNC=2), KT=2048, f32 C.
  auto* pvf  = gemm_pipe<2, 2, 2, 2, 2048, 1024, 1024, false, false>;
  constexpr int QK_LDS = 2 * (256 + 256) * 64 * 2;   // 131072
  constexpr int PV_LDS = 2 * (256 + 128) * 64 * 2;   //  98304
  (void)hipFuncSetAttribute((const void*)qk16,
      hipFuncAttributeMaxDynamicSharedMemorySize, QK_LDS);
  (void)hipFuncSetAttribute((const void*)qk32,
      hipFuncAttributeMaxDynamicSharedMemorySize, QK_LDS);
  (void)hipFuncSetAttribute((const void*)pvf,
      hipFuncAttributeMaxDynamicSharedMemorySize, PV_LDS);

  prep_kernel<<<18433, 256, 0, stream>>>(Q, K, V, tb, W, bias,
                                         Qb, Kb, VT, gate);
  if (f16path) {
    qk16<<<256, 512, QK_LDS, stream>>>(Qb, Kb, gate, nullptr, Sc);
    softmax16_kernel<<<8192, 256, 0, stream>>>(Sc, attn, attnb);
  } else {
    qk32<<<256, 512, QK_LDS, stream>>>(Qb, Kb, gate, attn, nullptr);
    softmax32_kernel<<<8192, 256, 0, stream>>>(attn, attnb);
  }
  pvf<<<256, 512, PV_LDS, stream>>>(attnb, VT, gate, out, nullptr);
}

// Round 17
// 129.468 us; speedup vs baseline: 1.1001x; 1.0154x over previous
//
#include <hip/hip_runtime.h>
#include <hip/hip_bf16.h>
#include <stdint.h>
#include <stddef.h>

#define B_  4
#define S_  2048
#define D_  1024
#define TB_ 128

typedef float v4f  __attribute__((ext_vector_type(4)));
typedef float v16f __attribute__((ext_vector_type(16)));
typedef short s16x4 __attribute__((ext_vector_type(4)));
typedef short s16x8 __attribute__((ext_vector_type(8)));

#define WAITV(n) asm volatile("s_waitcnt vmcnt(" #n ")" ::: "memory")

__device__ __forceinline__ unsigned short f2bf(float f) {
  union { float f; unsigned u; } x; x.f = f;
  unsigned u = x.u;
  unsigned r = (u + 0x7FFFu + ((u >> 16) & 1u)) >> 16;
  return (unsigned short)r;
}

__device__ __forceinline__ short f2h(float f) {
  union { _Float16 h; short s; } u;
  u.h = (_Float16)f;
  return u.s;
}

__device__ __forceinline__ float h2f(short s) {
  union { short s; _Float16 h; } u;
  u.s = s;
  return (float)u.h;
}

__device__ __forceinline__ void gld16(const void* g, void* l) {
  __builtin_amdgcn_global_load_lds(
      (const __attribute__((address_space(1))) unsigned int*)g,
      (__attribute__((address_space(3))) unsigned int*)l, 16, 0, 0);
}

// raw barrier (no vmcnt(0) drain) + motion fence
__device__ __forceinline__ void barrier_sync() {
  asm volatile("" ::: "memory");
  __builtin_amdgcn_s_barrier();
  asm volatile("" ::: "memory");
  __builtin_amdgcn_sched_barrier(0);
}

// ---------------- prep: gate + cvt(Q,K) + V^T, one dispatch ---------------
// cvt: 8 floats/thread (s16x8 store). vT: vectorized s16x4 stores, lane
// mapping keeps stores 128B-contiguous per 16-lane group; LDS reads <=2-way.
__global__ __launch_bounds__(256) void prep_kernel(
    const float* __restrict__ Q, const float* __restrict__ K,
    const float* __restrict__ V, const float* __restrict__ tb,
    const float* __restrict__ W, const float* __restrict__ bias,
    short* __restrict__ Qb, short* __restrict__ Kb,
    short* __restrict__ VT, float* __restrict__ gate) {
  __shared__ float tile[64][65];
  int bid = blockIdx.x;
  int t = threadIdx.x;
  if (bid < 8192) {                        // bulk f32->bf16 convert (Q or K)
    const float* src = bid < 4096 ? Q : K;
    short* dst = bid < 4096 ? Qb : Kb;
    size_t g = (size_t)(bid & 4095) * 256 + t;   // 8 floats each
    v4f va = *(const v4f*)(src + g * 8);
    v4f vb = *(const v4f*)(src + g * 8 + 4);
    s16x8 o;
    o[0] = (short)f2bf(va[0]); o[1] = (short)f2bf(va[1]);
    o[2] = (short)f2bf(va[2]); o[3] = (short)f2bf(va[3]);
    o[4] = (short)f2bf(vb[0]); o[5] = (short)f2bf(vb[1]);
    o[6] = (short)f2bf(vb[2]); o[7] = (short)f2bf(vb[3]);
    *(s16x8*)(dst + g * 8) = o;
  } else if (bid < 10240) {                // V [b][s][d] -> V^T [b][d][s]
    int v = bid - 8192;
    int b = v >> 9;
    int rem = v & 511;
    int s0 = (rem & 31) * 64, d0 = (rem >> 5) * 64;
    int tc = t & 63, tr4 = t >> 6;
    const float* src = V + ((size_t)b * S_ + s0) * D_ + d0;
    #pragma unroll
    for (int p = 0; p < 16; ++p) {
      int r = p * 4 + tr4;
      tile[r][tc] = src[(size_t)r * D_ + tc];   // tile[s_local][d_local]
    }
    __syncthreads();
    // store: lane l of wave w handles s-quad sq=l&15, d = w*16+p*4+(l>>4)
    short* dst = VT + ((size_t)b * D_ + d0) * S_ + s0;
    int w = t >> 6, l = t & 63;
    int sq = l & 15, dc = l >> 4;
    #pragma unroll
    for (int p = 0; p < 4; ++p) {
      int d = w * 16 + p * 4 + dc;
      s16x4 o;
      #pragma unroll
      for (int i = 0; i < 4; ++i)
        o[i] = (short)f2bf(tile[sq * 4 + i][d]);
      *(s16x4*)(dst + (size_t)d * S_ + sq * 4) = o;
    }
  } else {                                 // gate: sigmoid(tb @ W + b)
    int b = t >> 6, l = t & 63;
    float s = tb[b * TB_ + l] * W[l] + tb[b * TB_ + 64 + l] * W[64 + l];
    #pragma unroll
    for (int off = 32; off > 0; off >>= 1) s += __shfl_down(s, off, 64);
    if (l == 0) gate[b] = 1.0f / (1.0f + __expf(-(s + bias[0])));
  }
}

// ---------------- pipelined GEMM (32x32x16 MFMA): C = A . B^T -------------
// R9's verified structure (best measured): BK=64, 2 LDS buffers, counted
// vmcnt, XOR slot swizzle (rule 21), setprio clusters. CF16: epilogue
// writes f16 scores (half the write traffic) instead of f32 C.
template<int MFR, int NFR, int WNC, int BLOADS, int KT, int BROWS, int LDC,
         bool GATED, bool CF16>
__global__ __launch_bounds__(512, 2) void gemm_pipe(
    const short* __restrict__ Ag, const short* __restrict__ Bg,
    const float* __restrict__ gate, float* __restrict__ Cg,
    short* __restrict__ Sc) {
  extern __shared__ char lds[];
  constexpr int NT = KT / 64;             // K-tiles
  constexpr int BN = WNC * NFR * 32;      // B-tile rows
  constexpr int ABYTES = 256 * 128;       // 32 KB per K-tile
  constexpr int BBYTES = BN * 128;
  constexpr int BUFB = ABYTES + BBYTES;

  int wg = blockIdx.x;
  int swz = (wg & 7) * 32 + (wg >> 3);    // 256 wgs -> bijective XCD chunk
  int b = swz >> 6;
  int rem = swz & 63;
  int m0 = (rem >> 3) * 256;
  int n0 = (rem & 7) * BN;

  int tid = threadIdx.x;
  int w = tid >> 6, l = tid & 63;
  int wm = w / WNC, wn = w % WNC;
  int l7 = l & 7, col31 = l & 31, hi2 = l >> 5;

  const short* Ab = Ag + (size_t)b * S_ * KT + (size_t)m0 * KT;
  const short* Bb = Bg + (size_t)b * BROWS * KT + (size_t)n0 * KT;

  // staging: linear LDS dest; inverse-swizzled global chunk (rule #21)
  int srow8 = l >> 3;
  int schunk = (l7 ^ srow8) * 8;          // shorts

  v16f acc[MFR][NFR];
  #pragma unroll
  for (int m = 0; m < MFR; ++m)
    #pragma unroll
    for (int n = 0; n < NFR; ++n)
      #pragma unroll
      for (int j = 0; j < 16; ++j) acc[m][n][j] = 0.0f;

  auto stage = [&](int t, int buf) {
    char* La = lds + buf * BUFB;
    char* Lb = La + ABYTES;
    const short* As = Ab + (size_t)t * 64 + schunk;
    #pragma unroll
    for (int j = 0; j < 4; ++j) {
      int blk = w * 4 + j;
      gld16(As + (size_t)(blk * 8 + srow8) * KT, La + blk * 1024);
    }
    const short* Bs = Bb + (size_t)t * 64 + schunk;
    #pragma unroll
    for (int j = 0; j < BLOADS; ++j) {
      int blk = w * BLOADS + j;
      gld16(Bs + (size_t)(blk * 8 + srow8) * KT, Lb + blk * 1024);
    }
  };

  stage(0, 0);
  int cur = 0;
  for (int t = 0; t < NT; ++t) {
    if (t + 1 < NT) {
      stage(t + 1, cur ^ 1);              // prefetch stays in flight
      if constexpr (BLOADS == 4) WAITV(8); else WAITV(6);
    } else {
      WAITV(0);
    }
    barrier_sync();                       // publish tile t
    const char* Abase = lds + cur * BUFB;
    const char* Bbase = Abase + ABYTES;
    #pragma unroll
    for (int ks = 0; ks < 4; ++ks) {
      int slot = ((ks * 2 + hi2) ^ l7) * 16;
      s16x8 bfr[NFR], af[MFR];
      #pragma unroll
      for (int n = 0; n < NFR; ++n)
        bfr[n] = *(const s16x8*)(Bbase +
                 (size_t)(wn * (NFR * 32) + n * 32 + col31) * 128 + slot);
      #pragma unroll
      for (int m = 0; m < MFR; ++m)
        af[m] = *(const s16x8*)(Abase +
                 (size_t)(wm * (MFR * 32) + m * 32 + col31) * 128 + slot);
      __builtin_amdgcn_s_setprio(1);
      #pragma unroll
      for (int m = 0; m < MFR; ++m)
        #pragma unroll
        for (int n = 0; n < NFR; ++n)
          acc[m][n] = __builtin_amdgcn_mfma_f32_32x32x16_bf16(
              af[m], bfr[n], acc[m][n], 0, 0, 0);
      __builtin_amdgcn_s_setprio(0);
    }
    barrier_sync();                       // reads of buf[cur] done
    cur ^= 1;
  }

  float g = 1.0f;
  if constexpr (GATED) g = gate[b] * 0.03125f;   // sigmoid-gate / sqrt(1024)
  if constexpr (CF16) {
    short* Sb = Sc + (size_t)b * S_ * LDC +
                (size_t)(m0 + wm * (MFR * 32)) * LDC + n0 + wn * (NFR * 32);
    #pragma unroll
    for (int mf = 0; mf < MFR; ++mf)
      #pragma unroll
      for (int nf = 0; nf < NFR; ++nf) {
        int c = nf * 32 + col31;
        #pragma unroll
        for (int q = 0; q < 4; ++q)
          #pragma unroll
          for (int j = 0; j < 4; ++j) {
            int r = mf * 32 + q * 8 + 4 * hi2 + j;
            Sb[(size_t)r * LDC + c] = f2h(acc[mf][nf][q * 4 + j] * g);
          }
      }
  } else {
    float* Cb = Cg + (size_t)b * S_ * LDC +
                (size_t)(m0 + wm * (MFR * 32)) * LDC + n0 + wn * (NFR * 32);
    #pragma unroll
    for (int mf = 0; mf < MFR; ++mf)
      #pragma unroll
      for (int nf = 0; nf < NFR; ++nf) {
        int c = nf * 32 + col31;
        #pragma unroll
        for (int q = 0; q < 4; ++q)
          #pragma unroll
          for (int j = 0; j < 4; ++j) {
            int r = mf * 32 + q * 8 + 4 * hi2 + j;
            Cb[(size_t)r * LDC + c] = acc[mf][nf][q * 4 + j] * g;
          }
      }
  }
}

// ---------------- softmax (f16 scores): write f32 attn + bf16 P -----------
__global__ __launch_bounds__(256) void softmax16_kernel(
    const short* __restrict__ Sc, float* __restrict__ attn,
    short* __restrict__ attnb) {
  size_t row = blockIdx.x;
  const short* p = Sc + row * S_;
  int t = threadIdx.x;
  s16x8 raw = *(const s16x8*)(p + t * 8);
  float v[8];
  #pragma unroll
  for (int j = 0; j < 8; ++j) v[j] = h2f(raw[j]);
  float m = v[0];
  #pragma unroll
  for (int j = 1; j < 8; ++j) m = fmaxf(m, v[j]);
  #pragma unroll
  for (int off = 32; off > 0; off >>= 1) m = fmaxf(m, __shfl_xor(m, off, 64));
  __shared__ float rm[4], rs[4];
  if ((t & 63) == 0) rm[t >> 6] = m;
  __syncthreads();
  m = fmaxf(fmaxf(rm[0], rm[1]), fmaxf(rm[2], rm[3]));
  float e[8]; float sum = 0.0f;
  #pragma unroll
  for (int j = 0; j < 8; ++j) { e[j] = __expf(v[j] - m); sum += e[j]; }
  #pragma unroll
  for (int off = 32; off > 0; off >>= 1) sum += __shfl_xor(sum, off, 64);
  if ((t & 63) == 0) rs[t >> 6] = sum;
  __syncthreads();
  sum = rs[0] + rs[1] + rs[2] + rs[3];
  float inv = 1.0f / sum;
  v4f o0, o1;
  s16x8 ob;
  #pragma unroll
  for (int j = 0; j < 4; ++j) { o0[j] = e[j] * inv; ob[j] = (short)f2bf(o0[j]); }
  #pragma unroll
  for (int j = 0; j < 4; ++j) { o1[j] = e[4 + j] * inv; ob[4 + j] = (short)f2bf(o1[j]); }
  float* q = attn + row * S_;
  *(v4f*)(q + t * 8) = o0;
  *(v4f*)(q + t * 8 + 4) = o1;
  *(s16x8*)(attnb + row * S_ + t * 8) = ob;
}

// ---------------- fallback softmax (f32 scores in-place) ------------------
__global__ __launch_bounds__(256) void softmax32_kernel(
    float* __restrict__ attn, short* __restrict__ attnb) {
  size_t row = blockIdx.x;
  float* p = attn + row * S_;
  int t = threadIdx.x;
  v4f v0 = *(const v4f*)(p + t * 8);
  v4f v1 = *(const v4f*)(p + t * 8 + 4);
  float m = fmaxf(fmaxf(fmaxf(v0[0], v0[1]), fmaxf(v0[2], v0[3])),
                  fmaxf(fmaxf(v1[0], v1[1]), fmaxf(v1[2], v1[3])));
  #pragma unroll
  for (int off = 32; off > 0; off >>= 1) m = fmaxf(m, __shfl_xor(m, off, 64));
  __shared__ float rm[4], rs[4];
  if ((t & 63) == 0) rm[t >> 6] = m;
  __syncthreads();
  m = fmaxf(fmaxf(rm[0], rm[1]), fmaxf(rm[2], rm[3]));
  float e[8]; float sum = 0.0f;
  #pragma unroll
  for (int j = 0; j < 4; ++j) { e[j] = __expf(v0[j] - m); sum += e[j]; }
  #pragma unroll
  for (int j = 0; j < 4; ++j) { e[4 + j] = __expf(v1[j] - m); sum += e[4 + j]; }
  #pragma unroll
  for (int off = 32; off > 0; off >>= 1) sum += __shfl_xor(sum, off, 64);
  if ((t & 63) == 0) rs[t >> 6] = sum;
  __syncthreads();
  sum = rs[0] + rs[1] + rs[2] + rs[3];
  float inv = 1.0f / sum;
  s16x8 ob;
  #pragma unroll
  for (int j = 0; j < 4; ++j) { v0[j] = e[j] * inv; ob[j] = (short)f2bf(v0[j]); }
  #pragma unroll
  for (int j = 0; j < 4; ++j) { v1[j] = e[4 + j] * inv; ob[4 + j] = (short)f2bf(v1[j]); }
  *(v4f*)(p + t * 8) = v0;
  *(v4f*)(p + t * 8 + 4) = v1;
  *(s16x8*)(attnb + row * S_ + t * 8) = ob;
}

extern "C" void kernel_launch(void* const* d_in, const int* in_sizes, int n_in,
                              void* d_out, int out_size, void* d_ws, size_t ws_size,
                              hipStream_t stream) {
  (void)in_sizes; (void)n_in; (void)out_size;
  const float* Q  = (const float*)d_in[0];
  const float* K  = (const float*)d_in[1];
  const float* V  = (const float*)d_in[2];
  const float* tb = (const float*)d_in[3];
  const float* W  = (const float*)d_in[4];
  const float* bias = (const float*)d_in[5];

  float* out  = (float*)d_out;                       // [4,2048,1024]
  float* attn = out + (size_t)B_ * S_ * D_;          // [4,2048,2048]

  char* ws = (char*)d_ws;
  float* gate = (float*)ws;                          // 4 floats
  short* Qb = (short*)(ws + 256);                    // bf16 [4][2048][1024]
  short* Kb = Qb + (size_t)B_ * S_ * D_;             // bf16 [4][2048][1024]
  short* VT = Kb + (size_t)B_ * S_ * D_;             // bf16 [4][1024][2048]
  short* Sc = VT + (size_t)B_ * D_ * S_;             // f16 [4][2048][2048]
  short* attnb = Qb;                                 // reuse Qb+Kb: bf16 P

  const size_t NEED_F16 = 256 + (size_t)48 * 1024 * 1024
                              + (size_t)32 * 1024 * 1024;
  bool f16path = ws_size >= NEED_F16;

  // QK variants: f16-score epilogue (preferred) or f32 (fallback).
  auto* qk16 = gemm_pipe<4, 2, 4, 4, 1024, 2048, 2048, true, true>;
  auto* qk32 = gemm_pipe<4, 2, 4, 4, 1024, 2048, 2048, true, false>;
  // PV: tile 256x128 (MFR=2,NFR=2,WNC=2), KT=2048, f32 C.
  auto* pvf  = gemm_pipe<2, 2, 2, 2, 2048, 1024, 1024, false, false>;
  constexpr int QK_LDS = 2 * (256 + 256) * 64 * 2;   // 131072
  constexpr int PV_LDS = 2 * (256 + 128) * 64 * 2;   //  98304
  (void)hipFuncSetAttribute((const void*)qk16,
      hipFuncAttributeMaxDynamicSharedMemorySize, QK_LDS);
  (void)hipFuncSetAttribute((const void*)qk32,
      hipFuncAttributeMaxDynamicSharedMemorySize, QK_LDS);
  (void)hipFuncSetAttribute((const void*)pvf,
      hipFuncAttributeMaxDynamicSharedMemorySize, PV_LDS);

  prep_kernel<<<10241, 256, 0, stream>>>(Q, K, V, tb, W, bias,
                                         Qb, Kb, VT, gate);
  if (f16path) {
    qk16<<<256, 512, QK_LDS, stream>>>(Qb, Kb, gate, nullptr, Sc);
    softmax16_kernel<<<8192, 256, 0, stream>>>(Sc, attn, attnb);
  } else {
    qk32<<<256, 512, QK_LDS, stream>>>(Qb, Kb, gate, attn, nullptr);
    softmax32_kernel<<<8192, 256, 0, stream>>>(attn, attnb);
  }
  pvf<<<256, 512, PV_LDS, stream>>>(attnb, VT, gate, out, nullptr);
}